// Round 10
// baseline (1757.949 us; speedup 1.0000x reference)
//
#include <hip/hip_runtime.h>

#define NB 256
#define NO 32
#define NEE 32
#define NT 16
#define THREADS 512

typedef const float* fp;

struct Params {
  fp z;
  fp ee1w, ee1b, ee2w, ee2b, ee3w, ee3b;
  fp ne1w, ne1b, ne2w, ne2b, ne3w, ne3b, ne4w, ne4b;
  fp le1w, le1b, le2w, le2b, le3w, le3b;
  fp lt1w, lt1b, lt2w, lt2b, lt3w, lt3b, lt4w, lt4b, lt5w, lt5b;
  float* out;
  int tf;
};

__device__ __forceinline__ float frelu(float x) { return x > 0.f ? x : 0.f; }

// ---- LDS float offsets (dynamic block, 40448 floats = 158 KiB) ----
#define OFF_U    0       // 2048
#define OFF_V    2048    // 2048
#define OFF_AGG  4096    // 2048
#define OFF_H    6144    // 2048: 8 waves x 4 x 64
#define OFF_W2   8192    // 4096: pair layer2 swz (ee2 -> le2)
#define OFF_W3   12288   // 4096: pair layer3 swz (ee3 -> le3)
#define OFF_L1A  16384   // 4096: le1 rows 0-63 swz   (A1: src region)
#define OFF_L1B  20480   // 4096: le1 rows 64-127 swz
#define OFF_T1A  24576   // 4096: lt1 zc-half swz     (A3: ne1agg swz)
#define OFF_T1B  28672   // 4096: lt1 agg-half swz    (A3: ne2 swz)
#define OFF_T2   32768   // 4096: lt2 swz             (A3: ne3 nat + ne4 nat)
#define OFF_T3   36864   // 2048: lt3 natural [64][32]
#define OFF_T4   38912   // 512 : lt4 natural [32][16]
#define OFF_T5   39424   // 1024: lt5 natural [16][64]
#define LDS_FLOATS 40448

// stage nf4 float4s, natural layout
__device__ __forceinline__ void stageN(float* dst, const float* src, int nf4, int tid) {
  for (int i4 = tid; i4 < nf4; i4 += THREADS)
    *(float4*)(dst + i4 * 4) = *(const float4*)(src + i4 * 4);
}
// stage [64][64] matrix transposed+swizzled: [k][o] -> dst[o*64+((k>>2 ^ (o&15))<<2)+(k&3)]
__device__ __forceinline__ void stageSwz(float* dst, const float* src, int tid) {
#pragma unroll
  for (int r = 0; r < 2; ++r) {
    int i4 = tid + r * THREADS;
    int k = i4 >> 4;
    int o4 = (i4 & 15) << 2;
    float4 v = *(const float4*)(src + k * 64 + o4);
    int kc = k >> 2, j = k & 3;
    dst[(o4 + 0) * 64 + ((kc ^ ((o4 + 0) & 15)) << 2) + j] = v.x;
    dst[(o4 + 1) * 64 + ((kc ^ ((o4 + 1) & 15)) << 2) + j] = v.y;
    dst[(o4 + 2) * 64 + ((kc ^ ((o4 + 2) & 15)) << 2) + j] = v.z;
    dst[(o4 + 3) * 64 + ((kc ^ ((o4 + 3) & 15)) << 2) + j] = v.w;
  }
}

// 4-row dense, natural-layout LDS weights (col = this lane's output column)
template<int KC>
__device__ __forceinline__ void dense4L(const float* x0, const float* x1,
                                        const float* x2, const float* x3,
                                        const float* w, int ldw, int col, float o[4]) {
#pragma unroll
  for (int kc = 0; kc < KC; ++kc) {
    float w0 = w[(4 * kc + 0) * ldw + col];
    float w1 = w[(4 * kc + 1) * ldw + col];
    float w2 = w[(4 * kc + 2) * ldw + col];
    float w3 = w[(4 * kc + 3) * ldw + col];
    float4 a = *(const float4*)(x0 + 4 * kc);
    float4 b = *(const float4*)(x1 + 4 * kc);
    float4 c = *(const float4*)(x2 + 4 * kc);
    float4 d = *(const float4*)(x3 + 4 * kc);
    o[0] = fmaf(a.x, w0, o[0]); o[0] = fmaf(a.y, w1, o[0]); o[0] = fmaf(a.z, w2, o[0]); o[0] = fmaf(a.w, w3, o[0]);
    o[1] = fmaf(b.x, w0, o[1]); o[1] = fmaf(b.y, w1, o[1]); o[1] = fmaf(b.z, w2, o[1]); o[1] = fmaf(b.w, w3, o[1]);
    o[2] = fmaf(c.x, w0, o[2]); o[2] = fmaf(c.y, w1, o[2]); o[2] = fmaf(c.z, w2, o[2]); o[2] = fmaf(c.w, w3, o[2]);
    o[3] = fmaf(d.x, w0, o[3]); o[3] = fmaf(d.y, w1, o[3]); o[3] = fmaf(d.z, w2, o[3]); o[3] = fmaf(d.w, w3, o[3]);
  }
}

// 4-row dense, swizzled [64][64] LDS weights (b128 weight read per kc)
__device__ __forceinline__ void dense4S(const float* x0, const float* x1,
                                        const float* x2, const float* x3,
                                        const float* w, int lane, int swm, float o[4]) {
#pragma unroll
  for (int kc = 0; kc < 16; ++kc) {
    float4 ww = *(const float4*)(w + (lane << 6) + ((kc ^ swm) << 2));
    float4 a = *(const float4*)(x0 + 4 * kc);
    float4 b = *(const float4*)(x1 + 4 * kc);
    float4 c = *(const float4*)(x2 + 4 * kc);
    float4 d = *(const float4*)(x3 + 4 * kc);
    o[0] = fmaf(a.x, ww.x, o[0]); o[0] = fmaf(a.y, ww.y, o[0]); o[0] = fmaf(a.z, ww.z, o[0]); o[0] = fmaf(a.w, ww.w, o[0]);
    o[1] = fmaf(b.x, ww.x, o[1]); o[1] = fmaf(b.y, ww.y, o[1]); o[1] = fmaf(b.z, ww.z, o[1]); o[1] = fmaf(b.w, ww.w, o[1]);
    o[2] = fmaf(c.x, ww.x, o[2]); o[2] = fmaf(c.y, ww.y, o[2]); o[2] = fmaf(c.z, ww.z, o[2]); o[2] = fmaf(c.w, ww.w, o[2]);
    o[3] = fmaf(d.x, ww.x, o[3]); o[3] = fmaf(d.y, ww.y, o[3]); o[3] = fmaf(d.z, ww.z, o[3]); o[3] = fmaf(d.w, ww.w, o[3]);
  }
}

// Edge MLP over this wave's 64 pair slots (496 real + dummies(0,0): +e/-e cancels).
// 4 pairs in flight; W2/W3 swizzled LDS; indices by scalar unranking.
__device__ void pair_phase(float* lds, int wave, int lane, int swm,
                           float b1, float b2, float b3) {
  const float* sU = lds + OFF_U;
  const float* sV = lds + OFF_V;
  float* sAgg = lds + OFF_AGG;
  const float* wA = lds + OFF_W2;
  const float* wB = lds + OFF_W3;
  float* sH = lds + OFF_H + wave * 256;
  int pi = 0, rem = wave * 64;
  while (rem >= 31 - pi) { rem -= 31 - pi; ++pi; }
  int pj = pi + 1 + rem;
  int pp = wave * 64;
  for (int qd = 0; qd < 16; ++qd) {
    int i4[4], j4[4];
#pragma unroll
    for (int q = 0; q < 4; ++q) {
      bool real = (pp < 496);
      i4[q] = real ? pi : 0;
      j4[q] = real ? pj : 0;
      if (real) { ++pj; if (pj == 32) { ++pi; pj = pi + 1; } }
      ++pp;
    }
#pragma unroll
    for (int q = 0; q < 4; ++q)
      sH[q * 64 + lane] = frelu(sU[i4[q] * 64 + lane] + sV[j4[q] * 64 + lane] + b1);
    float a[4][4];
#pragma unroll
    for (int q = 0; q < 4; ++q) { a[q][0] = b2; a[q][1] = 0.f; a[q][2] = 0.f; a[q][3] = 0.f; }
#pragma unroll
    for (int kc = 0; kc < 16; ++kc) {
      float4 w = *(const float4*)(wA + (lane << 6) + ((kc ^ swm) << 2));
#pragma unroll
      for (int q = 0; q < 4; ++q) {
        float4 x = *(const float4*)(sH + q * 64 + 4 * kc);
        a[q][0] = fmaf(x.x, w.x, a[q][0]); a[q][1] = fmaf(x.y, w.y, a[q][1]);
        a[q][2] = fmaf(x.z, w.z, a[q][2]); a[q][3] = fmaf(x.w, w.w, a[q][3]);
      }
    }
#pragma unroll
    for (int q = 0; q < 4; ++q)
      sH[q * 64 + lane] = frelu((a[q][0] + a[q][1]) + (a[q][2] + a[q][3]));
#pragma unroll
    for (int q = 0; q < 4; ++q) { a[q][0] = b3; a[q][1] = 0.f; a[q][2] = 0.f; a[q][3] = 0.f; }
#pragma unroll
    for (int kc = 0; kc < 16; ++kc) {
      float4 w = *(const float4*)(wB + (lane << 6) + ((kc ^ swm) << 2));
#pragma unroll
      for (int q = 0; q < 4; ++q) {
        float4 x = *(const float4*)(sH + q * 64 + 4 * kc);
        a[q][0] = fmaf(x.x, w.x, a[q][0]); a[q][1] = fmaf(x.y, w.y, a[q][1]);
        a[q][2] = fmaf(x.z, w.z, a[q][2]); a[q][3] = fmaf(x.w, w.w, a[q][3]);
      }
    }
#pragma unroll
    for (int q = 0; q < 4; ++q) {
      float e3 = (a[q][0] + a[q][1]) + (a[q][2] + a[q][3]);
      atomicAdd(&sAgg[i4[q] * 64 + lane],  e3);
      atomicAdd(&sAgg[j4[q] * 64 + lane], -e3);
    }
  }
}

__global__ __launch_bounds__(THREADS) void rld_kernel(Params P) {
  extern __shared__ float lds[];
  const int b = blockIdx.x;
  const int tid = (int)threadIdx.x;
  const int lane = tid & 63;
  const int wave = tid >> 6;
  const int cc = lane & 31;
  const int c16 = lane & 15;
  const int swm = lane & 15;

  float* sU = lds + OFF_U;
  float* sV = lds + OFF_V;
  float* sAgg = lds + OFF_AGG;
  float* sHme = lds + OFF_H + wave * 256;
  const int i0 = wave, i1 = wave + 8, i2 = wave + 16, i3 = wave + 24;
  const float* zb = P.z + (size_t)b * NT * NO * NEE;

  // ===== A1: src[32,512] @ {ee1a, ee1b, ne1a} via staged 32-row chunks =====
  // src region = OFF_L1A (4096); chunk slots: OFF_W2 (ee1a), OFF_W2+2048 (ee1b), OFF_W3 (ne1a)
  float au[4] = {0, 0, 0, 0}, av[4] = {0, 0, 0, 0}, s1r[4] = {0, 0, 0, 0};
  for (int qq = 0; qq < 4; ++qq) {
    __syncthreads();
    for (int idx = tid; idx < 4096; idx += THREADS) {
      int i = idx >> 7, kk = idx & 127;
      int k = qq * 128 + kk, t = k >> 5, e = k & 31;
      float v = zb[(t * NO + i) * NEE + e];
      if (t > 0) v -= zb[((t - 1) * NO + i) * NEE + e];
      lds[OFF_L1A + i * 128 + kk] = v;
    }
    for (int c = 0; c < 4; ++c) {
      __syncthreads();
      {
        int r0 = qq * 128 + c * 32;
        int kk = tid >> 4, o4 = (tid & 15) << 2;
        *(float4*)(lds + OFF_W2 + kk * 64 + o4)        = *(const float4*)(P.ee1w + (r0 + kk) * 64 + o4);
        *(float4*)(lds + OFF_W2 + 2048 + kk * 64 + o4) = *(const float4*)(P.ee1w + (512 + r0 + kk) * 64 + o4);
        *(float4*)(lds + OFF_W3 + kk * 64 + o4)        = *(const float4*)(P.ne1w + (r0 + kk) * 64 + o4);
      }
      __syncthreads();
      const float* x0 = lds + OFF_L1A + i0 * 128 + c * 32;
      const float* x1 = lds + OFF_L1A + i1 * 128 + c * 32;
      const float* x2 = lds + OFF_L1A + i2 * 128 + c * 32;
      const float* x3 = lds + OFF_L1A + i3 * 128 + c * 32;
      dense4L<8>(x0, x1, x2, x3, lds + OFF_W2, 64, lane, au);
      dense4L<8>(x0, x1, x2, x3, lds + OFF_W2 + 2048, 64, lane, av);
      dense4L<8>(x0, x1, x2, x3, lds + OFF_W3, 64, lane, s1r);
    }
  }
  __syncthreads();
  sU[i0 * 64 + lane] = au[0]; sU[i1 * 64 + lane] = au[1];
  sU[i2 * 64 + lane] = au[2]; sU[i3 * 64 + lane] = au[3];
  sV[i0 * 64 + lane] = av[0]; sV[i1 * 64 + lane] = av[1];
  sV[i2 * 64 + lane] = av[2]; sV[i3 * 64 + lane] = av[3];
  sAgg[i0 * 64 + lane] = 0.f; sAgg[i1 * 64 + lane] = 0.f;
  sAgg[i2 * 64 + lane] = 0.f; sAgg[i3 * 64 + lane] = 0.f;
  stageSwz(lds + OFF_W2, P.ee2w, tid);
  stageSwz(lds + OFF_W3, P.ee3w, tid);
  float eb1 = P.ee1b[lane], eb2 = P.ee2b[lane], eb3 = P.ee3b[lane];
  __syncthreads();

  // ===== A2: ee edge MLP =====
  pair_phase(lds, wave, lane, swm, eb1, eb2, eb3);
  __syncthreads();

  // stage ne node weights
  stageSwz(lds + OFF_T1A, P.ne1w + 512 * 64, tid);   // ne1 agg-half, swz
  stageSwz(lds + OFF_T1B, P.ne2w, tid);              // ne2, swz
  stageN(lds + OFF_T2, P.ne3w, 512, tid);            // ne3 64x32 natural
  stageN(lds + OFF_T2 + 2048, P.ne4w, 256, tid);     // ne4 32x32 natural
  __syncthreads();

  // ===== A3: ne node MLP -> zci[4] =====
  float zci[4];
  {
    float nb1 = P.ne1b[lane], nb2 = P.ne2b[lane];
    float nb3 = P.ne3b[cc],   nb4 = P.ne4b[cc];
    float o1[4] = {s1r[0] + nb1, s1r[1] + nb1, s1r[2] + nb1, s1r[3] + nb1};
    dense4S(sAgg + i0 * 64, sAgg + i1 * 64, sAgg + i2 * 64, sAgg + i3 * 64, lds + OFF_T1A, lane, swm, o1);
    sU[i0 * 64 + lane] = frelu(o1[0]); sU[i1 * 64 + lane] = frelu(o1[1]);
    sU[i2 * 64 + lane] = frelu(o1[2]); sU[i3 * 64 + lane] = frelu(o1[3]);
    float o2[4] = {nb2, nb2, nb2, nb2};
    dense4S(sU + i0 * 64, sU + i1 * 64, sU + i2 * 64, sU + i3 * 64, lds + OFF_T1B, lane, swm, o2);
    sV[i0 * 64 + lane] = frelu(o2[0]); sV[i1 * 64 + lane] = frelu(o2[1]);
    sV[i2 * 64 + lane] = frelu(o2[2]); sV[i3 * 64 + lane] = frelu(o2[3]);
    float o3[4] = {nb3, nb3, nb3, nb3};
    dense4L<16>(sV + i0 * 64, sV + i1 * 64, sV + i2 * 64, sV + i3 * 64, lds + OFF_T2, 32, cc, o3);
    sU[i0 * 64 + cc] = frelu(o3[0]); sU[i1 * 64 + cc] = frelu(o3[1]);
    sU[i2 * 64 + cc] = frelu(o3[2]); sU[i3 * 64 + cc] = frelu(o3[3]);
    float o4[4] = {nb4, nb4, nb4, nb4};
    dense4L<8>(sU + i0 * 64, sU + i1 * 64, sU + i2 * 64, sU + i3 * 64, lds + OFF_T2 + 2048, 32, cc, o4);
    zci[0] = (lane < 32) ? zb[(15 * NO + i0) * NEE + lane] : o4[0];
    zci[1] = (lane < 32) ? zb[(15 * NO + i1) * NEE + lane] : o4[1];
    zci[2] = (lane < 32) ? zb[(15 * NO + i2) * NEE + lane] : o4[2];
    zci[3] = (lane < 32) ? zb[(15 * NO + i3) * NEE + lane] : o4[3];
  }
  __syncthreads();   // A3 reads done; safe to overwrite all weight regions

  // ===== stage ALL phase-B weights once (permanently resident) =====
  stageSwz(lds + OFF_W2,  P.le2w, tid);
  stageSwz(lds + OFF_W3,  P.le3w, tid);
  stageSwz(lds + OFF_L1A, P.le1w, tid);
  stageSwz(lds + OFF_L1B, P.le1w + 4096, tid);
  stageSwz(lds + OFF_T1A, P.lt1w, tid);
  stageSwz(lds + OFF_T1B, P.lt1w + 4096, tid);
  stageSwz(lds + OFF_T2,  P.lt2w, tid);
  stageN(lds + OFF_T3, P.lt3w, 512, tid);
  stageN(lds + OFF_T4, P.lt4w, 128, tid);
  stageN(lds + OFF_T5, P.lt5w, 256, tid);
  float gb1 = P.le1b[lane], gb2 = P.le2b[lane], gb3 = P.le3b[lane];
  float lb1 = P.lt1b[lane], lb2 = P.lt2b[lane];
  float lb3 = P.lt3b[cc],  lb4 = P.lt4b[c16], lb5 = P.lt5b[lane];
  float* outb = P.out + (size_t)b * P.tf * NO * NEE;
  __syncthreads();

  // initial u/v/agg for t=0 (own rows; zc bounced via own sH region)
  {
    sHme[lane] = zci[0]; sHme[64 + lane] = zci[1];
    sHme[128 + lane] = zci[2]; sHme[192 + lane] = zci[3];
    float ou[4] = {0, 0, 0, 0}, ov[4] = {0, 0, 0, 0};
    dense4S(sHme, sHme + 64, sHme + 128, sHme + 192, lds + OFF_L1A, lane, swm, ou);
    dense4S(sHme, sHme + 64, sHme + 128, sHme + 192, lds + OFF_L1B, lane, swm, ov);
    sU[i0 * 64 + lane] = ou[0]; sU[i1 * 64 + lane] = ou[1];
    sU[i2 * 64 + lane] = ou[2]; sU[i3 * 64 + lane] = ou[3];
    sV[i0 * 64 + lane] = ov[0]; sV[i1 * 64 + lane] = ov[1];
    sV[i2 * 64 + lane] = ov[2]; sV[i3 * 64 + lane] = ov[3];
    sAgg[i0 * 64 + lane] = 0.f; sAgg[i1 * 64 + lane] = 0.f;
    sAgg[i2 * 64 + lane] = 0.f; sAgg[i3 * 64 + lane] = 0.f;
  }

  // ===== Phase B: t_future steps, zero staging, 2 barriers/step =====
  for (int t = 0; t < P.tf; ++t) {
    __syncthreads();                 // u/v/agg visible to all waves
    pair_phase(lds, wave, lane, swm, gb1, gb2, gb3);
    __syncthreads();                 // agg complete
    // lt node MLP (own rows; sU/sV as scratch), state update, output, next u/v
    sHme[lane] = zci[0]; sHme[64 + lane] = zci[1];
    sHme[128 + lane] = zci[2]; sHme[192 + lane] = zci[3];
    float o1[4] = {lb1, lb1, lb1, lb1};
    dense4S(sHme, sHme + 64, sHme + 128, sHme + 192, lds + OFF_T1A, lane, swm, o1);
    dense4S(sAgg + i0 * 64, sAgg + i1 * 64, sAgg + i2 * 64, sAgg + i3 * 64, lds + OFF_T1B, lane, swm, o1);
    sU[i0 * 64 + lane] = frelu(o1[0]); sU[i1 * 64 + lane] = frelu(o1[1]);
    sU[i2 * 64 + lane] = frelu(o1[2]); sU[i3 * 64 + lane] = frelu(o1[3]);
    float o2[4] = {lb2, lb2, lb2, lb2};
    dense4S(sU + i0 * 64, sU + i1 * 64, sU + i2 * 64, sU + i3 * 64, lds + OFF_T2, lane, swm, o2);
    sV[i0 * 64 + lane] = frelu(o2[0]); sV[i1 * 64 + lane] = frelu(o2[1]);
    sV[i2 * 64 + lane] = frelu(o2[2]); sV[i3 * 64 + lane] = frelu(o2[3]);
    float o3[4] = {lb3, lb3, lb3, lb3};
    dense4L<16>(sV + i0 * 64, sV + i1 * 64, sV + i2 * 64, sV + i3 * 64, lds + OFF_T3, 32, cc, o3);
    sU[i0 * 64 + cc] = frelu(o3[0]); sU[i1 * 64 + cc] = frelu(o3[1]);
    sU[i2 * 64 + cc] = frelu(o3[2]); sU[i3 * 64 + cc] = frelu(o3[3]);
    float o4[4] = {lb4, lb4, lb4, lb4};
    dense4L<8>(sU + i0 * 64, sU + i1 * 64, sU + i2 * 64, sU + i3 * 64, lds + OFF_T4, 16, c16, o4);
    sV[i0 * 64 + c16] = frelu(o4[0]); sV[i1 * 64 + c16] = frelu(o4[1]);
    sV[i2 * 64 + c16] = frelu(o4[2]); sV[i3 * 64 + c16] = frelu(o4[3]);
    float o5[4] = {lb5, lb5, lb5, lb5};
    dense4L<4>(sV + i0 * 64, sV + i1 * 64, sV + i2 * 64, sV + i3 * 64, lds + OFF_T5, 64, lane, o5);
    zci[0] += o5[0]; zci[1] += o5[1]; zci[2] += o5[2]; zci[3] += o5[3];
    if (lane < 32) {
      outb[(t * NO + i0) * NEE + lane] = zci[0];
      outb[(t * NO + i1) * NEE + lane] = zci[1];
      outb[(t * NO + i2) * NEE + lane] = zci[2];
      outb[(t * NO + i3) * NEE + lane] = zci[3];
    }
    // next-step u/v + agg zero (own rows; loop-top barrier publishes)
    sHme[lane] = zci[0]; sHme[64 + lane] = zci[1];
    sHme[128 + lane] = zci[2]; sHme[192 + lane] = zci[3];
    float ou[4] = {0, 0, 0, 0}, ov[4] = {0, 0, 0, 0};
    dense4S(sHme, sHme + 64, sHme + 128, sHme + 192, lds + OFF_L1A, lane, swm, ou);
    dense4S(sHme, sHme + 64, sHme + 128, sHme + 192, lds + OFF_L1B, lane, swm, ov);
    sU[i0 * 64 + lane] = ou[0]; sU[i1 * 64 + lane] = ou[1];
    sU[i2 * 64 + lane] = ou[2]; sU[i3 * 64 + lane] = ou[3];
    sV[i0 * 64 + lane] = ov[0]; sV[i1 * 64 + lane] = ov[1];
    sV[i2 * 64 + lane] = ov[2]; sV[i3 * 64 + lane] = ov[3];
    sAgg[i0 * 64 + lane] = 0.f; sAgg[i1 * 64 + lane] = 0.f;
    sAgg[i2 * 64 + lane] = 0.f; sAgg[i3 * 64 + lane] = 0.f;
  }
}

extern "C" void kernel_launch(void* const* d_in, const int* in_sizes, int n_in,
                              void* d_out, int out_size, void* d_ws, size_t ws_size,
                              hipStream_t stream) {
  (void)in_sizes; (void)n_in; (void)d_ws; (void)ws_size;
  Params P;
  int q = 0;
  P.z    = (fp)d_in[q++];
  P.ee1w = (fp)d_in[q++]; P.ee1b = (fp)d_in[q++];
  P.ee2w = (fp)d_in[q++]; P.ee2b = (fp)d_in[q++];
  P.ee3w = (fp)d_in[q++]; P.ee3b = (fp)d_in[q++];
  P.ne1w = (fp)d_in[q++]; P.ne1b = (fp)d_in[q++];
  P.ne2w = (fp)d_in[q++]; P.ne2b = (fp)d_in[q++];
  P.ne3w = (fp)d_in[q++]; P.ne3b = (fp)d_in[q++];
  P.ne4w = (fp)d_in[q++]; P.ne4b = (fp)d_in[q++];
  P.le1w = (fp)d_in[q++]; P.le1b = (fp)d_in[q++];
  P.le2w = (fp)d_in[q++]; P.le2b = (fp)d_in[q++];
  P.le3w = (fp)d_in[q++]; P.le3b = (fp)d_in[q++];
  P.lt1w = (fp)d_in[q++]; P.lt1b = (fp)d_in[q++];
  P.lt2w = (fp)d_in[q++]; P.lt2b = (fp)d_in[q++];
  P.lt3w = (fp)d_in[q++]; P.lt3b = (fp)d_in[q++];
  P.lt4w = (fp)d_in[q++]; P.lt4b = (fp)d_in[q++];
  P.lt5w = (fp)d_in[q++]; P.lt5b = (fp)d_in[q++];
  P.out = (float*)d_out;
  P.tf = out_size / (NB * NO * NEE);
  if (P.tf < 1) P.tf = 1;
  const int shbytes = LDS_FLOATS * 4;   // 161792 B < 160 KiB CU limit
  hipFuncSetAttribute(reinterpret_cast<const void*>(rld_kernel),
                      hipFuncAttributeMaxDynamicSharedMemorySize, shbytes);
  hipLaunchKernelGGL(rld_kernel, dim3(NB), dim3(THREADS), shbytes, stream, P);
}